// Round 7
// baseline (124.164 us; speedup 1.0000x reference)
//
#include <hip/hip_runtime.h>
#include <math.h>

// Problem geometry
#define N_IMG   48          // B*C = 8*6
#define IMG_W   512
#define IMG_H   512
#define IMG_HW  (IMG_W*IMG_H)
#define OUT_W   506         // 512 - 6 (VALID 7x7)
#define OUT_H   506
#define BAND_H  46          // output rows per band; 46*11 = 506
#define N_BANDS 11
#define K1C     0.01f
#define K2C     0.03f

// ws layout (doubles first, then uints):
//   wsd[0..127]   = sum |diff| partial slots
//   wsd[128..255] = sum diff^2 partial slots
//   wsd[256..447] = per-image SSIM sums (img*4 + band&3)
//   wsu (byte offset 3584): [0..47] per-image min (ordered map), [48..95] max
#define SLOT_S1   0
#define SLOT_S2   128
#define SLOT_SSIM 256
#define N_DBL     448
#define WSU_OFF   3584

__device__ __forceinline__ unsigned fmap(float f) {
  unsigned u = __float_as_uint(f);
  return (u & 0x80000000u) ? ~u : (u | 0x80000000u);
}
__device__ __forceinline__ float funmap(unsigned u) {
  return (u & 0x80000000u) ? __uint_as_float(u & 0x7FFFFFFFu)
                           : __uint_as_float(~u);
}

__global__ void init_ws(double* wsd, unsigned* wsu) {
  int t = threadIdx.x;
  if (t < N_DBL) wsd[t] = 0.0;
  if (t < 48) { wsu[t] = 0xFFFFFFFFu; wsu[48 + t] = 0u; }
}

// Pass 1 (fused stats): per-image min/max of y_true*mask + global MAE/MSE.
// 128 chunks/image * 48 images = 6144 blocks, 256 threads, 2 float4/thread
// per array. Partials -> 128 slots (chain depth 48).
__global__ __launch_bounds__(256) void stat_kernel(
    const float4* __restrict__ p4, const float4* __restrict__ t4,
    const float4* __restrict__ m4, double* __restrict__ wsd,
    unsigned* __restrict__ wsu) {
  const int img = blockIdx.x >> 7;
  const int chunk = blockIdx.x & 127;
  const size_t base = (size_t)img * (IMG_HW / 4) + (size_t)chunk * 512;
  const int t = threadIdx.x;

  float s1 = 0.f, s2 = 0.f, mn = INFINITY, mx = -INFINITY;
#pragma unroll
  for (int k = 0; k < 2; ++k) {
    size_t idx = base + (size_t)k * 256 + t;
    float4 a = p4[idx], b = t4[idx], m = m4[idx];
    {
      float d = (a.x - b.x) * m.x, v = b.x * m.x;
      s1 += fabsf(d); s2 = fmaf(d, d, s2);
      mn = fminf(mn, v); mx = fmaxf(mx, v);
    }
    {
      float d = (a.y - b.y) * m.y, v = b.y * m.y;
      s1 += fabsf(d); s2 = fmaf(d, d, s2);
      mn = fminf(mn, v); mx = fmaxf(mx, v);
    }
    {
      float d = (a.z - b.z) * m.z, v = b.z * m.z;
      s1 += fabsf(d); s2 = fmaf(d, d, s2);
      mn = fminf(mn, v); mx = fmaxf(mx, v);
    }
    {
      float d = (a.w - b.w) * m.w, v = b.w * m.w;
      s1 += fabsf(d); s2 = fmaf(d, d, s2);
      mn = fminf(mn, v); mx = fmaxf(mx, v);
    }
  }

#pragma unroll
  for (int off = 32; off; off >>= 1) {
    s1 += __shfl_down(s1, off);
    s2 += __shfl_down(s2, off);
    mn = fminf(mn, __shfl_down(mn, off));
    mx = fmaxf(mx, __shfl_down(mx, off));
  }
  __shared__ float r1[4], r2[4], rmn[4], rmx[4];
  int wave = t >> 6, lane = t & 63;
  if (lane == 0) { r1[wave] = s1; r2[wave] = s2; rmn[wave] = mn; rmx[wave] = mx; }
  __syncthreads();
  if (t == 0) {
    float S1 = r1[0] + r1[1] + r1[2] + r1[3];
    float S2 = r2[0] + r2[1] + r2[2] + r2[3];
    float MN = fminf(fminf(rmn[0], rmn[1]), fminf(rmn[2], rmn[3]));
    float MX = fmaxf(fmaxf(rmx[0], rmx[1]), fmaxf(rmx[2], rmx[3]));
    int slot = blockIdx.x & 127;
    atomicAdd(&wsd[SLOT_S1 + slot], (double)S1);
    atomicAdd(&wsd[SLOT_S2 + slot], (double)S2);
    atomicMin(&wsu[img], fmap(MN));
    atomicMax(&wsu[48 + img], fmap(MX));
  }
}

// Pass 2: SSIM only, proven R3 iteration structure, QUARTER columns.
// One block per (image, band, quarter): 48*11*4 = 2112 blocks of 128
// threads (2 waves -> cheap barriers, 8+ independent blocks/CU).
// Quarters q=0..2 produce 127 output cols, q=3 produces 125 (sum 506).
// Separable 7x7 box: LDS-staged rows (double-buffered) + 6-deep register
// ring with STATIC slot indices (row loop unrolled by 6). Raw-sum algebra
// (1/49^2, 1/(49*48) cancel; C1,C2 pre-scaled by 2401/2352).

#define SSIM_ROW(J, ROW, WARM, LAST)                                        \
  {                                                                          \
    float nx0 = 0.f, ny0 = 0.f, nx1 = 0.f, ny1 = 0.f;                        \
    const bool pf = !(LAST);                                                 \
    if (pf) {                                                                \
      size_t off = rowbase + (size_t)((ROW) + 1) * IMG_W + t;                \
      float m0 = mk[off];                                                    \
      nx0 = yp[off] * m0; ny0 = yt[off] * m0;                                \
      if (extra) {                                                           \
        size_t o2 = off + 128;                                               \
        float m1 = mk[o2];                                                   \
        nx1 = yp[o2] * m1; ny1 = yt[o2] * m1;                                \
      }                                                                      \
    }                                                                        \
    float hx = 0.f, hy = 0.f, hxx = 0.f, hyy = 0.f, hxy = 0.f;               \
    if (prod) {                                                              \
      _Pragma("unroll")                                                      \
      for (int jj = 0; jj < 7; ++jj) {                                       \
        float xv = lx[(J) & 1][t + jj], yv = ly[(J) & 1][t + jj];            \
        hx += xv; hy += yv;                                                  \
        hxx = fmaf(xv, xv, hxx);                                             \
        hyy = fmaf(yv, yv, hyy);                                             \
        hxy = fmaf(xv, yv, hxy);                                             \
      }                                                                      \
    }                                                                        \
    if (!(WARM)) {                                                           \
      float sx = vx_ + hx, sy = vy_ + hy;                                    \
      float sxx = vxx + hxx, syy = vyy + hyy, sxy = vxy + hxy;               \
      if (prod) {                                                            \
        float p = sx * sy;                                                   \
        float q = fmaf(sx, sx, sy * sy);                                     \
        float tt = sxx + syy;                                                \
        float A1 = fmaf(2.f, p, C1q);                                        \
        float A2 = fmaf(-2.f, p, fmaf(98.f, sxy, C2q));                      \
        float B1 = q + C1q;                                                  \
        float B2 = fmaf(49.f, tt, C2q - q);                                  \
        acc = fmaf(A1 * A2, __builtin_amdgcn_rcpf(B1 * B2), acc);            \
      }                                                                      \
      vx_ += hx - rx[(J)]; vy_ += hy - ry[(J)];                              \
      vxx += hxx - rxx[(J)]; vyy += hyy - ryy[(J)]; vxy += hxy - rxy[(J)];   \
    } else {                                                                 \
      vx_ += hx; vy_ += hy; vxx += hxx; vyy += hyy; vxy += hxy;              \
    }                                                                        \
    rx[(J)] = hx; ry[(J)] = hy;                                              \
    rxx[(J)] = hxx; ryy[(J)] = hyy; rxy[(J)] = hxy;                          \
    if (pf) {                                                                \
      lx[1 - ((J) & 1)][t] = nx0; ly[1 - ((J) & 1)][t] = ny0;                \
      if (extra) {                                                           \
        lx[1 - ((J) & 1)][t + 128] = nx1; ly[1 - ((J) & 1)][t + 128] = ny1;  \
      }                                                                      \
    }                                                                        \
    __syncthreads();                                                         \
  }

__global__ __launch_bounds__(128) void ssim_kernel(
    const float* __restrict__ yp, const float* __restrict__ yt,
    const float* __restrict__ mk, double* __restrict__ wsd,
    const unsigned* __restrict__ wsu) {
  const int bid = blockIdx.x;
  const int img = bid / (4 * N_BANDS);
  const int rem = bid % (4 * N_BANDS);
  const int band = rem >> 2;
  const int q = rem & 3;
  const int c0 = q * 127;
  const int r0 = band * BAND_H;
  const size_t rowbase = (size_t)img * IMG_HW + (size_t)r0 * IMG_W + c0;
  const int t = threadIdx.x;
  const int qout = (q == 3) ? 125 : 127;       // output cols this quarter
  const bool extra = (t < qout + 6 - 128);     // staged cols 128.. (5 or 3)
  const bool prod = (t < qout);

  const float d = funmap(wsu[48 + img]) - funmap(wsu[img]);
  const float C1q = (K1C * d) * (K1C * d) * 2401.0f;   // C1 * 49^2
  const float C2q = (K2C * d) * (K2C * d) * 2352.0f;   // C2 * 49*48

  __shared__ float lx[2][134];
  __shared__ float ly[2][134];

  float rx[6] = {0,0,0,0,0,0}, ry[6] = {0,0,0,0,0,0};
  float rxx[6] = {0,0,0,0,0,0}, ryy[6] = {0,0,0,0,0,0}, rxy[6] = {0,0,0,0,0,0};
  float vx_ = 0.f, vy_ = 0.f, vxx = 0.f, vyy = 0.f, vxy = 0.f;
  float acc = 0.f;

  // stage input row 0 into buffer 0
  {
    size_t off = rowbase + t;
    float m0 = mk[off];
    lx[0][t] = yp[off] * m0; ly[0][t] = yt[off] * m0;
    if (extra) {
      size_t o2 = off + 128;
      float m1 = mk[o2];
      lx[0][t + 128] = yp[o2] * m1; ly[0][t + 128] = yt[o2] * m1;
    }
  }
  __syncthreads();

  // warm-up rows 0..5 (ring slots 0..5, no output)
  SSIM_ROW(0, 0, true, false)
  SSIM_ROW(1, 1, true, false)
  SSIM_ROW(2, 2, true, false)
  SSIM_ROW(3, 3, true, false)
  SSIM_ROW(4, 4, true, false)
  SSIM_ROW(5, 5, true, false)

  // output rows: input rows 6..51, slot = row mod 6 (static per position)
  for (int g = 0; g < 8; ++g) {
    const int rbase = 6 + 6 * g;
    SSIM_ROW(0, rbase + 0, false, false)
    SSIM_ROW(1, rbase + 1, false, false)
    SSIM_ROW(2, rbase + 2, false, false)
    SSIM_ROW(3, rbase + 3, false, (rbase + 3) == 51)
    if (rbase + 4 < 52) SSIM_ROW(4, rbase + 4, false, false)
    if (rbase + 5 < 52) SSIM_ROW(5, rbase + 5, false, false)
  }

  // block reduction (2 waves) -> per-image accumulator
#pragma unroll
  for (int off = 32; off; off >>= 1) acc += __shfl_down(acc, off);
  __shared__ float warr[2];
  int wave = t >> 6, lane = t & 63;
  if (lane == 0) warr[wave] = acc;
  __syncthreads();
  if (t == 0) {
    float s = warr[0] + warr[1];
    atomicAdd(&wsd[SLOT_SSIM + img * 4 + (band & 3)], (double)s);  // depth 11
  }
}

__global__ void finalize_kernel(const double* __restrict__ wsd,
                                float* __restrict__ out) {
  if (threadIdx.x == 0 && blockIdx.x == 0) {
    const double N = (double)N_IMG * (double)IMG_HW;   // 12582912
    double mae = 0.0, mse = 0.0, ssum = 0.0;
    for (int i = 0; i < 128; ++i) { mae += wsd[SLOT_S1 + i]; mse += wsd[SLOT_S2 + i]; }
    mae /= N; mse /= N;
    for (int i = 0; i < 192; ++i) ssum += wsd[SLOT_SSIM + i];
    double smean = ssum / ((double)OUT_W * (double)OUT_H * (double)N_IMG);
    double ssim_loss = 1.0 - smean;
    double total = 1.0 * mae + 0.5 * mse + 0.2 * ssim_loss;
    out[0] = (float)total;
    out[1] = (float)mae;
    out[2] = (float)mse;
    out[3] = (float)ssim_loss;
  }
}

extern "C" void kernel_launch(void* const* d_in, const int* in_sizes, int n_in,
                              void* d_out, int out_size, void* d_ws,
                              size_t ws_size, hipStream_t stream) {
  const float* yp = (const float*)d_in[0];
  const float* yt = (const float*)d_in[1];
  const float* mk = (const float*)d_in[2];
  float* out = (float*)d_out;
  double* wsd = (double*)d_ws;
  unsigned* wsu = (unsigned*)((char*)d_ws + WSU_OFF);

  hipLaunchKernelGGL(init_ws, dim3(1), dim3(512), 0, stream, wsd, wsu);
  hipLaunchKernelGGL(stat_kernel, dim3(N_IMG * 128), dim3(256), 0, stream,
                     (const float4*)yp, (const float4*)yt, (const float4*)mk,
                     wsd, wsu);
  hipLaunchKernelGGL(ssim_kernel, dim3(N_IMG * N_BANDS * 4), dim3(128), 0,
                     stream, yp, yt, mk, wsd, wsu);
  hipLaunchKernelGGL(finalize_kernel, dim3(1), dim3(64), 0, stream, wsd, out);
}

// Round 8
// 95.293 us; speedup vs baseline: 1.3030x; 1.3030x over previous
//
#include <hip/hip_runtime.h>
#include <math.h>

// Problem geometry
#define N_IMG   48          // B*C = 8*6
#define IMG_W   512
#define IMG_H   512
#define IMG_HW  (IMG_W*IMG_H)
#define OUT_W   506         // 512 - 6 (VALID 7x7)
#define OUT_H   506
#define BAND_H  46          // output rows per band; 46*11 = 506
#define N_BANDS 11
#define N_STRIP 9           // 9 strips of 58 output cols (last = 42)
#define K1C     0.01f
#define K2C     0.03f

// ws layout (doubles first, then uints):
//   wsd[0..63]    = sum |diff| partial slots
//   wsd[64..127]  = sum diff^2 partial slots
//   wsd[128..511] = per-image SSIM sums (img*8 + slot)
//   wsu (byte offset 4096): [0..47] per-image min (ordered map), [48..95] max
#define SLOT_S1   0
#define SLOT_S2   64
#define SLOT_SSIM 128
#define N_DBL     512
#define WSU_OFF   4096

__device__ __forceinline__ unsigned fmap(float f) {
  unsigned u = __float_as_uint(f);
  return (u & 0x80000000u) ? ~u : (u | 0x80000000u);
}
__device__ __forceinline__ float funmap(unsigned u) {
  return (u & 0x80000000u) ? __uint_as_float(u & 0x7FFFFFFFu)
                           : __uint_as_float(~u);
}
__device__ __forceinline__ float lanef(int addr, float v) {
  return __int_as_float(__builtin_amdgcn_ds_bpermute(addr, __float_as_int(v)));
}

__global__ void init_ws(double* wsd, unsigned* wsu) {
  int t = threadIdx.x;
  if (t < N_DBL) wsd[t] = 0.0;
  if (t < 48) { wsu[t] = 0xFFFFFFFFu; wsu[48 + t] = 0u; }
}

// Pass 1 (EXACT R3-proven config): per-image min/max of y_true*mask +
// global MAE/MSE. 64 chunks/image * 48 images = 3072 blocks, 256 threads,
// 4 float4/thread/array. Partials -> 64 slots (chain depth 48).
__global__ __launch_bounds__(256) void stat_kernel(
    const float4* __restrict__ p4, const float4* __restrict__ t4,
    const float4* __restrict__ m4, double* __restrict__ wsd,
    unsigned* __restrict__ wsu) {
  const int img = blockIdx.x >> 6;
  const int chunk = blockIdx.x & 63;
  const size_t base = (size_t)img * (IMG_HW / 4) + (size_t)chunk * (IMG_HW / 256);
  const int t = threadIdx.x;

  float s1 = 0.f, s2 = 0.f, mn = INFINITY, mx = -INFINITY;
#pragma unroll
  for (int k = 0; k < 4; ++k) {
    size_t idx = base + (size_t)k * 256 + t;
    float4 a = p4[idx], b = t4[idx], m = m4[idx];
    {
      float d = (a.x - b.x) * m.x, v = b.x * m.x;
      s1 += fabsf(d); s2 = fmaf(d, d, s2);
      mn = fminf(mn, v); mx = fmaxf(mx, v);
    }
    {
      float d = (a.y - b.y) * m.y, v = b.y * m.y;
      s1 += fabsf(d); s2 = fmaf(d, d, s2);
      mn = fminf(mn, v); mx = fmaxf(mx, v);
    }
    {
      float d = (a.z - b.z) * m.z, v = b.z * m.z;
      s1 += fabsf(d); s2 = fmaf(d, d, s2);
      mn = fminf(mn, v); mx = fmaxf(mx, v);
    }
    {
      float d = (a.w - b.w) * m.w, v = b.w * m.w;
      s1 += fabsf(d); s2 = fmaf(d, d, s2);
      mn = fminf(mn, v); mx = fmaxf(mx, v);
    }
  }

#pragma unroll
  for (int off = 32; off; off >>= 1) {
    s1 += __shfl_down(s1, off);
    s2 += __shfl_down(s2, off);
    mn = fminf(mn, __shfl_down(mn, off));
    mx = fmaxf(mx, __shfl_down(mx, off));
  }
  __shared__ float r1[4], r2[4], rmn[4], rmx[4];
  int wave = t >> 6, lane = t & 63;
  if (lane == 0) { r1[wave] = s1; r2[wave] = s2; rmn[wave] = mn; rmx[wave] = mx; }
  __syncthreads();
  if (t == 0) {
    float S1 = r1[0] + r1[1] + r1[2] + r1[3];
    float S2 = r2[0] + r2[1] + r2[2] + r2[3];
    float MN = fminf(fminf(rmn[0], rmn[1]), fminf(rmn[2], rmn[3]));
    float MX = fmaxf(fmaxf(rmx[0], rmx[1]), fmaxf(rmx[2], rmx[3]));
    int slot = blockIdx.x & 63;
    atomicAdd(&wsd[SLOT_S1 + slot], (double)S1);
    atomicAdd(&wsd[SLOT_S2 + slot], (double)S2);
    atomicMin(&wsu[img], fmap(MN));
    atomicMax(&wsu[48 + img], fmap(MX));
  }
}

// Pass 2: SSIM, wave-autonomous, ZERO barriers, ZERO LDS.
// Block = 64 threads = 1 wave. Grid = 48 img * 11 bands * 9 strips = 4752.
// Lane = column within a 64-wide strip (58 producers + 6 halo lanes).
// Horizontal 7-taps via ds_bpermute (wave-lockstep, no sync, no vmcnt
// drain anywhere) -> global loads prefetch 2 rows ahead in named A/B
// register sets and stay in flight across iterations.
// Vertical 7-window via 6-deep register ring with STATIC slots
// (period-6 unroll; parity A/B matches row%2). Raw-sum SSIM algebra.

#define SEC(J, ROW, PS, WARM, RELOAD)                                        \
  {                                                                          \
    float x = PS##p * PS##m, y = PS##t * PS##m;                              \
    if (RELOAD) {                                                            \
      size_t o_ = base + (size_t)((ROW) + 2) * IMG_W;                        \
      PS##p = yp[o_]; PS##t = yt[o_]; PS##m = mk[o_];                        \
    }                                                                        \
    float x1 = lanef(a1, x), x2 = lanef(a2, x), x3 = lanef(a3, x);           \
    float x4 = lanef(a4, x), x5 = lanef(a5, x), x6 = lanef(a6, x);           \
    float y1 = lanef(a1, y), y2 = lanef(a2, y), y3 = lanef(a3, y);           \
    float y4 = lanef(a4, y), y5 = lanef(a5, y), y6 = lanef(a6, y);           \
    float hx = ((x + x1) + (x2 + x3)) + ((x4 + x5) + x6);                    \
    float hy = ((y + y1) + (y2 + y3)) + ((y4 + y5) + y6);                    \
    float hxx = x * x, hyy = y * y, hxy = x * y;                             \
    hxx = fmaf(x1, x1, hxx); hyy = fmaf(y1, y1, hyy); hxy = fmaf(x1, y1, hxy);\
    hxx = fmaf(x2, x2, hxx); hyy = fmaf(y2, y2, hyy); hxy = fmaf(x2, y2, hxy);\
    hxx = fmaf(x3, x3, hxx); hyy = fmaf(y3, y3, hyy); hxy = fmaf(x3, y3, hxy);\
    hxx = fmaf(x4, x4, hxx); hyy = fmaf(y4, y4, hyy); hxy = fmaf(x4, y4, hxy);\
    hxx = fmaf(x5, x5, hxx); hyy = fmaf(y5, y5, hyy); hxy = fmaf(x5, y5, hxy);\
    hxx = fmaf(x6, x6, hxx); hyy = fmaf(y6, y6, hyy); hxy = fmaf(x6, y6, hxy);\
    if (!(WARM)) {                                                           \
      float sx = vx_ + hx, sy = vy_ + hy;                                    \
      float sxx = vxx + hxx, syy = vyy + hyy, sxy = vxy + hxy;               \
      if (prod) {                                                            \
        float p_ = sx * sy;                                                  \
        float q_ = fmaf(sx, sx, sy * sy);                                    \
        float tt_ = sxx + syy;                                               \
        float A1_ = fmaf(2.f, p_, C1q);                                      \
        float A2_ = fmaf(-2.f, p_, fmaf(98.f, sxy, C2q));                    \
        float B1_ = q_ + C1q;                                                \
        float B2_ = fmaf(49.f, tt_, C2q - q_);                               \
        acc = fmaf(A1_ * A2_, __builtin_amdgcn_rcpf(B1_ * B2_), acc);        \
      }                                                                      \
      vx_ += hx - rx[(J)]; vy_ += hy - ry[(J)];                              \
      vxx += hxx - rxx[(J)]; vyy += hyy - ryy[(J)]; vxy += hxy - rxy[(J)];   \
    } else {                                                                 \
      vx_ += hx; vy_ += hy; vxx += hxx; vyy += hyy; vxy += hxy;              \
    }                                                                        \
    rx[(J)] = hx; ry[(J)] = hy;                                              \
    rxx[(J)] = hxx; ryy[(J)] = hyy; rxy[(J)] = hxy;                          \
  }

__global__ __launch_bounds__(64) void ssim_kernel(
    const float* __restrict__ yp, const float* __restrict__ yt,
    const float* __restrict__ mk, double* __restrict__ wsd,
    const unsigned* __restrict__ wsu) {
  const int bid = blockIdx.x;
  const int img = bid / (N_BANDS * N_STRIP);
  const int rem = bid % (N_BANDS * N_STRIP);
  const int band = rem / N_STRIP;
  const int strip = rem % N_STRIP;
  const int lane = threadIdx.x;
  const int c0 = strip * 58;
  const int col = min(c0 + lane, IMG_W - 1);     // clamp (strip 8 halo)
  const int r0 = band * BAND_H;
  const size_t base = (size_t)img * IMG_HW + (size_t)r0 * IMG_W + col;
  const int nout = (strip < 8) ? 58 : 42;        // 8*58 + 42 = 506
  const bool prod = (lane < nout);

  // bpermute byte addresses for neighbor pulls (hoisted out of the loop)
  const int a1 = (lane + 1) << 2, a2 = (lane + 2) << 2, a3 = (lane + 3) << 2;
  const int a4 = (lane + 4) << 2, a5 = (lane + 5) << 2, a6 = (lane + 6) << 2;

  const float d = funmap(wsu[48 + img]) - funmap(wsu[img]);
  const float C1q = (K1C * d) * (K1C * d) * 2401.0f;   // C1 * 49^2
  const float C2q = (K2C * d) * (K2C * d) * 2352.0f;   // C2 * 49*48

  float rx[6] = {0,0,0,0,0,0}, ry[6] = {0,0,0,0,0,0};
  float rxx[6] = {0,0,0,0,0,0}, ryy[6] = {0,0,0,0,0,0}, rxy[6] = {0,0,0,0,0,0};
  float vx_ = 0.f, vy_ = 0.f, vxx = 0.f, vyy = 0.f, vxy = 0.f;
  float acc = 0.f;

  // Prologue: prefetch rows 0 (A) and 1 (B); steady depth = 2 rows in flight.
  float Ap = yp[base], At = yt[base], Am = mk[base];
  float Bp = yp[base + IMG_W], Bt = yt[base + IMG_W], Bm = mk[base + IMG_W];

  // warm-up rows 0..5 (ring slots 0..5; consume row R, reload row R+2)
  SEC(0, 0, A, true, true)
  SEC(1, 1, B, true, true)
  SEC(2, 2, A, true, true)
  SEC(3, 3, B, true, true)
  SEC(4, 4, A, true, true)
  SEC(5, 5, B, true, true)

  // rows 6..47: 7 groups of 6 (reload rows 8..49, always valid)
  for (int g = 0; g < 7; ++g) {
    const int rbase = 6 + 6 * g;
    SEC(0, rbase + 0, A, false, true)
    SEC(1, rbase + 1, B, false, true)
    SEC(2, rbase + 2, A, false, true)
    SEC(3, rbase + 3, B, false, true)
    SEC(4, rbase + 4, A, false, true)
    SEC(5, rbase + 5, B, false, true)
  }
  // tail rows 48..51 (48,49 reload 50,51; 50,51 no reload)
  SEC(0, 48, A, false, true)
  SEC(1, 49, B, false, true)
  SEC(2, 50, A, false, false)
  SEC(3, 51, B, false, false)

  // wave reduction -> per-image slotted accumulator (no barrier needed)
#pragma unroll
  for (int off = 32; off; off >>= 1) acc += __shfl_down(acc, off);
  if (lane == 0)
    atomicAdd(&wsd[SLOT_SSIM + img * 8 + (rem & 7)], (double)acc);
}

__global__ void finalize_kernel(const double* __restrict__ wsd,
                                float* __restrict__ out) {
  if (threadIdx.x == 0 && blockIdx.x == 0) {
    const double N = (double)N_IMG * (double)IMG_HW;   // 12582912
    double mae = 0.0, mse = 0.0, ssum = 0.0;
    for (int i = 0; i < 64; ++i) { mae += wsd[SLOT_S1 + i]; mse += wsd[SLOT_S2 + i]; }
    mae /= N; mse /= N;
    for (int i = 0; i < 384; ++i) ssum += wsd[SLOT_SSIM + i];
    double smean = ssum / ((double)OUT_W * (double)OUT_H * (double)N_IMG);
    double ssim_loss = 1.0 - smean;
    double total = 1.0 * mae + 0.5 * mse + 0.2 * ssim_loss;
    out[0] = (float)total;
    out[1] = (float)mae;
    out[2] = (float)mse;
    out[3] = (float)ssim_loss;
  }
}

extern "C" void kernel_launch(void* const* d_in, const int* in_sizes, int n_in,
                              void* d_out, int out_size, void* d_ws,
                              size_t ws_size, hipStream_t stream) {
  const float* yp = (const float*)d_in[0];
  const float* yt = (const float*)d_in[1];
  const float* mk = (const float*)d_in[2];
  float* out = (float*)d_out;
  double* wsd = (double*)d_ws;
  unsigned* wsu = (unsigned*)((char*)d_ws + WSU_OFF);

  hipLaunchKernelGGL(init_ws, dim3(1), dim3(512), 0, stream, wsd, wsu);
  hipLaunchKernelGGL(stat_kernel, dim3(N_IMG * 64), dim3(256), 0, stream,
                     (const float4*)yp, (const float4*)yt, (const float4*)mk,
                     wsd, wsu);
  hipLaunchKernelGGL(ssim_kernel, dim3(N_IMG * N_BANDS * N_STRIP), dim3(64),
                     0, stream, yp, yt, mk, wsd, wsu);
  hipLaunchKernelGGL(finalize_kernel, dim3(1), dim3(64), 0, stream, wsd, out);
}

// Round 9
// 93.529 us; speedup vs baseline: 1.3275x; 1.0189x over previous
//
#include <hip/hip_runtime.h>
#include <math.h>

// Problem geometry
#define N_IMG   48          // B*C = 8*6
#define IMG_W   512
#define IMG_H   512
#define IMG_HW  (IMG_W*IMG_H)
#define OUT_W   506         // 512 - 6 (VALID 7x7)
#define OUT_H   506
#define BAND_H  46          // output rows per band; 46*11 = 506
#define N_BANDS 11
#define N_STRIP 9           // 9 strips of 58 output cols (last = 42)
#define K1C     0.01f
#define K2C     0.03f

// ws layout (doubles first, then uints):
//   wsd[0..127]   = sum |diff| partial slots
//   wsd[128..255] = sum diff^2 partial slots
//   wsd[256..639] = per-image SSIM sums (img*8 + slot)
//   wsu (byte offset 5120): [0..47] per-image min (ordered map), [48..95] max
#define SLOT_S1   0
#define SLOT_S2   128
#define SLOT_SSIM 256
#define N_DBL     640
#define WSU_OFF   5120

__device__ __forceinline__ unsigned fmap(float f) {
  unsigned u = __float_as_uint(f);
  return (u & 0x80000000u) ? ~u : (u | 0x80000000u);
}
__device__ __forceinline__ float funmap(unsigned u) {
  return (u & 0x80000000u) ? __uint_as_float(u & 0x7FFFFFFFu)
                           : __uint_as_float(~u);
}
__device__ __forceinline__ float lanef(int addr, float v) {
  return __int_as_float(__builtin_amdgcn_ds_bpermute(addr, __float_as_int(v)));
}

__global__ void init_ws(double* wsd, unsigned* wsu) {
  int t = threadIdx.x;
  if (t < N_DBL) wsd[t] = 0.0;
  if (t < 48) { wsu[t] = 0xFFFFFFFFu; wsu[48 + t] = 0u; }
}

// Pass 1: per-image min/max of y_true*mask ONLY (yt + mk, 100 MB).
// 64 chunks/image * 48 images = 3072 blocks, 256 threads, 4 float4/thread.
__global__ __launch_bounds__(256) void range_kernel(
    const float4* __restrict__ t4, const float4* __restrict__ m4,
    unsigned* __restrict__ wsu) {
  const int img = blockIdx.x >> 6;
  const int chunk = blockIdx.x & 63;
  const size_t base = (size_t)img * (IMG_HW / 4) + (size_t)chunk * (IMG_HW / 256);
  const int t = threadIdx.x;

  float mn = INFINITY, mx = -INFINITY;
#pragma unroll
  for (int k = 0; k < 4; ++k) {
    size_t idx = base + (size_t)k * 256 + t;
    float4 b = t4[idx], m = m4[idx];
    float v0 = b.x * m.x, v1 = b.y * m.y, v2 = b.z * m.z, v3 = b.w * m.w;
    mn = fminf(fminf(fminf(mn, v0), fminf(v1, v2)), v3);
    mx = fmaxf(fmaxf(fmaxf(mx, v0), fmaxf(v1, v2)), v3);
  }
#pragma unroll
  for (int off = 32; off; off >>= 1) {
    mn = fminf(mn, __shfl_down(mn, off));
    mx = fmaxf(mx, __shfl_down(mx, off));
  }
  __shared__ float rmn[4], rmx[4];
  int wave = t >> 6, lane = t & 63;
  if (lane == 0) { rmn[wave] = mn; rmx[wave] = mx; }
  __syncthreads();
  if (t == 0) {
    float MN = fminf(fminf(rmn[0], rmn[1]), fminf(rmn[2], rmn[3]));
    float MX = fmaxf(fmaxf(rmx[0], rmx[1]), fmaxf(rmx[2], rmx[3]));
    atomicMin(&wsu[img], fmap(MN));
    atomicMax(&wsu[48 + img], fmap(MX));
  }
}

// Pass 2: SSIM + fused MAE/MSE, wave-autonomous, ZERO barriers, ZERO LDS.
// Block = 64 threads = 1 wave. Grid = 48 img * 11 bands * 9 strips = 4752.
// Lane = column within a 64-wide strip (58 producers + 6 halo lanes).
// Horizontal 7-taps via ds_bpermute; loads prefetch 2 rows ahead in named
// A/B register sets. Vertical 7-window via 6-deep register ring with
// STATIC slots (period-6 unroll). Raw-sum SSIM algebra.
// MAE/MSE: diff = x - y on the registers the SSIM math consumes anyway
// (4 VALU/owned element, no structural change). Exact-once ownership:
//   cols: strips 0..7 own lanes 0..57; strip 8 owns lanes 0..47.
//   rows: staged rows 0..45 always owned; 46..51 owned iff last band.

#define SEC(J, ROW, PS, WARM, RELOAD, OWNR)                                  \
  {                                                                          \
    float x = PS##p * PS##m, y = PS##t * PS##m;                              \
    if ((OWNR) && mown) {                                                    \
      float df_ = x - y;                                                     \
      bs1 += fabsf(df_); bs2 = fmaf(df_, df_, bs2);                          \
    }                                                                        \
    if (RELOAD) {                                                            \
      size_t o_ = base + (size_t)((ROW) + 2) * IMG_W;                        \
      PS##p = yp[o_]; PS##t = yt[o_]; PS##m = mk[o_];                        \
    }                                                                        \
    float x1 = lanef(a1, x), x2 = lanef(a2, x), x3 = lanef(a3, x);           \
    float x4 = lanef(a4, x), x5 = lanef(a5, x), x6 = lanef(a6, x);           \
    float y1 = lanef(a1, y), y2 = lanef(a2, y), y3 = lanef(a3, y);           \
    float y4 = lanef(a4, y), y5 = lanef(a5, y), y6 = lanef(a6, y);           \
    float hx = ((x + x1) + (x2 + x3)) + ((x4 + x5) + x6);                    \
    float hy = ((y + y1) + (y2 + y3)) + ((y4 + y5) + y6);                    \
    float hxx = x * x, hyy = y * y, hxy = x * y;                             \
    hxx = fmaf(x1, x1, hxx); hyy = fmaf(y1, y1, hyy); hxy = fmaf(x1, y1, hxy);\
    hxx = fmaf(x2, x2, hxx); hyy = fmaf(y2, y2, hyy); hxy = fmaf(x2, y2, hxy);\
    hxx = fmaf(x3, x3, hxx); hyy = fmaf(y3, y3, hyy); hxy = fmaf(x3, y3, hxy);\
    hxx = fmaf(x4, x4, hxx); hyy = fmaf(y4, y4, hyy); hxy = fmaf(x4, y4, hxy);\
    hxx = fmaf(x5, x5, hxx); hyy = fmaf(y5, y5, hyy); hxy = fmaf(x5, y5, hxy);\
    hxx = fmaf(x6, x6, hxx); hyy = fmaf(y6, y6, hyy); hxy = fmaf(x6, y6, hxy);\
    if (!(WARM)) {                                                           \
      float sx = vx_ + hx, sy = vy_ + hy;                                    \
      float sxx = vxx + hxx, syy = vyy + hyy, sxy = vxy + hxy;               \
      if (prod) {                                                            \
        float p_ = sx * sy;                                                  \
        float q_ = fmaf(sx, sx, sy * sy);                                    \
        float tt_ = sxx + syy;                                               \
        float A1_ = fmaf(2.f, p_, C1q);                                      \
        float A2_ = fmaf(-2.f, p_, fmaf(98.f, sxy, C2q));                    \
        float B1_ = q_ + C1q;                                                \
        float B2_ = fmaf(49.f, tt_, C2q - q_);                               \
        acc = fmaf(A1_ * A2_, __builtin_amdgcn_rcpf(B1_ * B2_), acc);        \
      }                                                                      \
      vx_ += hx - rx[(J)]; vy_ += hy - ry[(J)];                              \
      vxx += hxx - rxx[(J)]; vyy += hyy - ryy[(J)]; vxy += hxy - rxy[(J)];   \
    } else {                                                                 \
      vx_ += hx; vy_ += hy; vxx += hxx; vyy += hyy; vxy += hxy;              \
    }                                                                        \
    rx[(J)] = hx; ry[(J)] = hy;                                              \
    rxx[(J)] = hxx; ryy[(J)] = hyy; rxy[(J)] = hxy;                          \
  }

__global__ __launch_bounds__(64) void ssim_kernel(
    const float* __restrict__ yp, const float* __restrict__ yt,
    const float* __restrict__ mk, double* __restrict__ wsd,
    const unsigned* __restrict__ wsu) {
  const int bid = blockIdx.x;
  const int img = bid / (N_BANDS * N_STRIP);
  const int rem = bid % (N_BANDS * N_STRIP);
  const int band = rem / N_STRIP;
  const int strip = rem % N_STRIP;
  const int lane = threadIdx.x;
  const int c0 = strip * 58;
  const int col = min(c0 + lane, IMG_W - 1);     // clamp (strip 8 halo)
  const int r0 = band * BAND_H;
  const size_t base = (size_t)img * IMG_HW + (size_t)r0 * IMG_W + col;
  const int nout = (strip < 8) ? 58 : 42;        // 8*58 + 42 = 506
  const bool prod = (lane < nout);
  const bool mown = (strip < 8) ? (lane < 58) : (lane < 48);  // MAE/MSE owner
  const bool lastband = (band == N_BANDS - 1);

  // bpermute byte addresses for neighbor pulls (hoisted out of the loop)
  const int a1 = (lane + 1) << 2, a2 = (lane + 2) << 2, a3 = (lane + 3) << 2;
  const int a4 = (lane + 4) << 2, a5 = (lane + 5) << 2, a6 = (lane + 6) << 2;

  const float d = funmap(wsu[48 + img]) - funmap(wsu[img]);
  const float C1q = (K1C * d) * (K1C * d) * 2401.0f;   // C1 * 49^2
  const float C2q = (K2C * d) * (K2C * d) * 2352.0f;   // C2 * 49*48

  float rx[6] = {0,0,0,0,0,0}, ry[6] = {0,0,0,0,0,0};
  float rxx[6] = {0,0,0,0,0,0}, ryy[6] = {0,0,0,0,0,0}, rxy[6] = {0,0,0,0,0,0};
  float vx_ = 0.f, vy_ = 0.f, vxx = 0.f, vyy = 0.f, vxy = 0.f;
  float acc = 0.f, bs1 = 0.f, bs2 = 0.f;

  // Prologue: prefetch rows 0 (A) and 1 (B); steady depth = 2 rows in flight.
  float Ap = yp[base], At = yt[base], Am = mk[base];
  float Bp = yp[base + IMG_W], Bt = yt[base + IMG_W], Bm = mk[base + IMG_W];

  // warm-up rows 0..5 (ring slots 0..5; consume row R, reload row R+2)
  SEC(0, 0, A, true, true, 1)
  SEC(1, 1, B, true, true, 1)
  SEC(2, 2, A, true, true, 1)
  SEC(3, 3, B, true, true, 1)
  SEC(4, 4, A, true, true, 1)
  SEC(5, 5, B, true, true, 1)

  // rows 6..47: 7 groups of 6 (reload rows 8..49, always valid; all owned
  // except rows 46,47 in group g=6 which are owned iff last band)
  for (int g = 0; g < 6; ++g) {
    const int rbase = 6 + 6 * g;
    SEC(0, rbase + 0, A, false, true, 1)
    SEC(1, rbase + 1, B, false, true, 1)
    SEC(2, rbase + 2, A, false, true, 1)
    SEC(3, rbase + 3, B, false, true, 1)
    SEC(4, rbase + 4, A, false, true, 1)
    SEC(5, rbase + 5, B, false, true, 1)
  }
  // group g=6: rows 42..47 (46,47 conditional ownership)
  SEC(0, 42, A, false, true, 1)
  SEC(1, 43, B, false, true, 1)
  SEC(2, 44, A, false, true, 1)
  SEC(3, 45, B, false, true, 1)
  SEC(4, 46, A, false, true, lastband)
  SEC(5, 47, B, false, true, lastband)
  // tail rows 48..51 (48,49 reload 50,51; 50,51 no reload; all conditional)
  SEC(0, 48, A, false, true, lastband)
  SEC(1, 49, B, false, true, lastband)
  SEC(2, 50, A, false, false, lastband)
  SEC(3, 51, B, false, false, lastband)

  // wave reduction -> slotted accumulators (no barrier needed)
#pragma unroll
  for (int off = 32; off; off >>= 1) {
    acc += __shfl_down(acc, off);
    bs1 += __shfl_down(bs1, off);
    bs2 += __shfl_down(bs2, off);
  }
  if (lane == 0) {
    atomicAdd(&wsd[SLOT_SSIM + img * 8 + (rem & 7)], (double)acc);
    atomicAdd(&wsd[SLOT_S1 + (bid & 127)], (double)bs1);
    atomicAdd(&wsd[SLOT_S2 + (bid & 127)], (double)bs2);
  }
}

__global__ void finalize_kernel(const double* __restrict__ wsd,
                                float* __restrict__ out) {
  if (threadIdx.x == 0 && blockIdx.x == 0) {
    const double N = (double)N_IMG * (double)IMG_HW;   // 12582912
    double mae = 0.0, mse = 0.0, ssum = 0.0;
    for (int i = 0; i < 128; ++i) { mae += wsd[SLOT_S1 + i]; mse += wsd[SLOT_S2 + i]; }
    mae /= N; mse /= N;
    for (int i = 0; i < 384; ++i) ssum += wsd[SLOT_SSIM + i];
    double smean = ssum / ((double)OUT_W * (double)OUT_H * (double)N_IMG);
    double ssim_loss = 1.0 - smean;
    double total = 1.0 * mae + 0.5 * mse + 0.2 * ssim_loss;
    out[0] = (float)total;
    out[1] = (float)mae;
    out[2] = (float)mse;
    out[3] = (float)ssim_loss;
  }
}

extern "C" void kernel_launch(void* const* d_in, const int* in_sizes, int n_in,
                              void* d_out, int out_size, void* d_ws,
                              size_t ws_size, hipStream_t stream) {
  const float* yp = (const float*)d_in[0];
  const float* yt = (const float*)d_in[1];
  const float* mk = (const float*)d_in[2];
  float* out = (float*)d_out;
  double* wsd = (double*)d_ws;
  unsigned* wsu = (unsigned*)((char*)d_ws + WSU_OFF);

  hipLaunchKernelGGL(init_ws, dim3(1), dim3(1024), 0, stream, wsd, wsu);
  hipLaunchKernelGGL(range_kernel, dim3(N_IMG * 64), dim3(256), 0, stream,
                     (const float4*)yt, (const float4*)mk, wsu);
  hipLaunchKernelGGL(ssim_kernel, dim3(N_IMG * N_BANDS * N_STRIP), dim3(64),
                     0, stream, yp, yt, mk, wsd, wsu);
  hipLaunchKernelGGL(finalize_kernel, dim3(1), dim3(64), 0, stream, wsd, out);
}

// Round 10
// 87.081 us; speedup vs baseline: 1.4258x; 1.0740x over previous
//
#include <hip/hip_runtime.h>
#include <math.h>

// Problem geometry
#define N_IMG   48          // B*C = 8*6
#define IMG_W   512
#define IMG_H   512
#define IMG_HW  (IMG_W*IMG_H)
#define OUT_W   506         // 512 - 6 (VALID 7x7)
#define OUT_H   506
#define BAND_H  46          // output rows per band; 46*11 = 506
#define N_BANDS 11
#define N_STRIP 5           // strips of 102,102,102,100,100 output cols
#define K1C     0.01f
#define K2C     0.03f

// ws layout (doubles first, then uints):
//   wsd[0..127]   = sum |diff| partial slots
//   wsd[128..255] = sum diff^2 partial slots
//   wsd[256..639] = per-image SSIM sums (img*8 + slot)
//   wsu (byte offset 5120): [0..47] per-image min (ordered map), [48..95] max
#define SLOT_S1   0
#define SLOT_S2   128
#define SLOT_SSIM 256
#define N_DBL     640
#define WSU_OFF   5120

__device__ __forceinline__ unsigned fmap(float f) {
  unsigned u = __float_as_uint(f);
  return (u & 0x80000000u) ? ~u : (u | 0x80000000u);
}
__device__ __forceinline__ float funmap(unsigned u) {
  return (u & 0x80000000u) ? __uint_as_float(u & 0x7FFFFFFFu)
                           : __uint_as_float(~u);
}
__device__ __forceinline__ float lanef(int addr, float v) {
  return __int_as_float(__builtin_amdgcn_ds_bpermute(addr, __float_as_int(v)));
}

__global__ void init_ws(double* wsd, unsigned* wsu) {
  int t = threadIdx.x;
  if (t < N_DBL) wsd[t] = 0.0;
  if (t < 48) { wsu[t] = 0xFFFFFFFFu; wsu[48 + t] = 0u; }
}

// Pass 1 (unchanged from R8): per-image min/max of y_true*mask (100 MB).
__global__ __launch_bounds__(256) void range_kernel(
    const float4* __restrict__ t4, const float4* __restrict__ m4,
    unsigned* __restrict__ wsu) {
  const int img = blockIdx.x >> 6;
  const int chunk = blockIdx.x & 63;
  const size_t base = (size_t)img * (IMG_HW / 4) + (size_t)chunk * (IMG_HW / 256);
  const int t = threadIdx.x;

  float mn = INFINITY, mx = -INFINITY;
#pragma unroll
  for (int k = 0; k < 4; ++k) {
    size_t idx = base + (size_t)k * 256 + t;
    float4 b = t4[idx], m = m4[idx];
    float v0 = b.x * m.x, v1 = b.y * m.y, v2 = b.z * m.z, v3 = b.w * m.w;
    mn = fminf(fminf(fminf(mn, v0), fminf(v1, v2)), v3);
    mx = fmaxf(fmaxf(fmaxf(mx, v0), fmaxf(v1, v2)), v3);
  }
#pragma unroll
  for (int off = 32; off; off >>= 1) {
    mn = fminf(mn, __shfl_down(mn, off));
    mx = fmaxf(mx, __shfl_down(mx, off));
  }
  __shared__ float rmn[4], rmx[4];
  int wave = t >> 6, lane = t & 63;
  if (lane == 0) { rmn[wave] = mn; rmx[wave] = mx; }
  __syncthreads();
  if (t == 0) {
    float MN = fminf(fminf(rmn[0], rmn[1]), fminf(rmn[2], rmn[3]));
    float MX = fmaxf(fmaxf(rmx[0], rmx[1]), fmaxf(rmx[2], rmx[3]));
    atomicMin(&wsu[img], fmap(MN));
    atomicMax(&wsu[48 + img], fmap(MX));
  }
}

// Pass 2: SSIM + fused MAE/MSE, wave-autonomous, 2 COLUMNS PER LANE.
// Block = 64 threads = 1 wave. Grid = 48 img * 11 bands * 5 strips = 2640.
// Lane owns cols (c0+2l, c0+2l+1) via float2 loads. Neighbor data for the
// 7-tap windows of BOTH columns comes from lanes l+1..l+3 (6 bpermutes per
// 2 cols per array = half the DS ops of the 1-col/lane version). Shared
// 6-term partial sums serve both columns. Vertical 7-window via 6-deep
// register ring, static slots (period-6 unroll). Raw-sum SSIM algebra.
// MAE/MSE fused on load registers; exact-once ownership:
//   cols: strips 0..3 own their nout cols; strip 4 owns cols 406..511.
//   rows: rows 0..45 always owned; 46..51 owned iff last band.

#define SEC(J, ROW, PS, WARM, RELOAD, OWNR)                                  \
  {                                                                          \
    float xe = PS##p.x * PS##m.x, xo = PS##p.y * PS##m.y;                    \
    float ye = PS##t.x * PS##m.x, yo = PS##t.y * PS##m.y;                    \
    if ((OWNR) && mown) {                                                    \
      float de_ = xe - ye; bs1 += fabsf(de_); bs2 = fmaf(de_, de_, bs2);     \
      float do_ = xo - yo; bs1 += fabsf(do_); bs2 = fmaf(do_, do_, bs2);     \
    }                                                                        \
    if (RELOAD) {                                                            \
      size_t o_ = base2 + (size_t)((ROW) + 2) * (IMG_W / 2);                 \
      PS##p = yp2[o_]; PS##t = yt2[o_]; PS##m = mk2[o_];                     \
    }                                                                        \
    float xe1 = lanef(a1, xe), xo1 = lanef(a1, xo);                          \
    float ye1 = lanef(a1, ye), yo1 = lanef(a1, yo);                          \
    float xe2 = lanef(a2, xe), xo2 = lanef(a2, xo);                          \
    float ye2 = lanef(a2, ye), yo2 = lanef(a2, yo);                          \
    float xe3 = lanef(a3, xe), xo3 = lanef(a3, xo);                          \
    float ye3 = lanef(a3, ye), yo3 = lanef(a3, yo);                          \
    float cx = ((xo + xe1) + (xo1 + xe2)) + (xo2 + xe3);                     \
    float cy = ((yo + ye1) + (yo1 + ye2)) + (yo2 + ye3);                     \
    float hxe = xe + cx, hxo = cx + xo3;                                     \
    float hye = ye + cy, hyo = cy + yo3;                                     \
    float cxx = xo * xo;                                                     \
    cxx = fmaf(xe1, xe1, cxx); cxx = fmaf(xo1, xo1, cxx);                    \
    cxx = fmaf(xe2, xe2, cxx); cxx = fmaf(xo2, xo2, cxx);                    \
    cxx = fmaf(xe3, xe3, cxx);                                               \
    float cyy = yo * yo;                                                     \
    cyy = fmaf(ye1, ye1, cyy); cyy = fmaf(yo1, yo1, cyy);                    \
    cyy = fmaf(ye2, ye2, cyy); cyy = fmaf(yo2, yo2, cyy);                    \
    cyy = fmaf(ye3, ye3, cyy);                                               \
    float cxy = xo * yo;                                                     \
    cxy = fmaf(xe1, ye1, cxy); cxy = fmaf(xo1, yo1, cxy);                    \
    cxy = fmaf(xe2, ye2, cxy); cxy = fmaf(xo2, yo2, cxy);                    \
    cxy = fmaf(xe3, ye3, cxy);                                               \
    float hxxe = fmaf(xe, xe, cxx), hxxo = fmaf(xo3, xo3, cxx);              \
    float hyye = fmaf(ye, ye, cyy), hyyo = fmaf(yo3, yo3, cyy);              \
    float hxye = fmaf(xe, ye, cxy), hxyo = fmaf(xo3, yo3, cxy);              \
    if (!(WARM)) {                                                           \
      if (prod) {                                                            \
        float sx_ = vxe + hxe, sy_ = vye + hye;                              \
        float sxx_ = vxxe + hxxe, syy_ = vyye + hyye, sxy_ = vxye + hxye;    \
        float p_ = sx_ * sy_;                                                \
        float q_ = fmaf(sx_, sx_, sy_ * sy_);                                \
        float tt_ = sxx_ + syy_;                                             \
        float A1_ = fmaf(2.f, p_, C1q);                                      \
        float A2_ = fmaf(-2.f, p_, fmaf(98.f, sxy_, C2q));                   \
        float B1_ = q_ + C1q;                                                \
        float B2_ = fmaf(49.f, tt_, C2q - q_);                               \
        acc = fmaf(A1_ * A2_, __builtin_amdgcn_rcpf(B1_ * B2_), acc);        \
        sx_ = vxo + hxo; sy_ = vyo + hyo;                                    \
        sxx_ = vxxo + hxxo; syy_ = vyyo + hyyo; sxy_ = vxyo + hxyo;          \
        p_ = sx_ * sy_;                                                      \
        q_ = fmaf(sx_, sx_, sy_ * sy_);                                      \
        tt_ = sxx_ + syy_;                                                   \
        A1_ = fmaf(2.f, p_, C1q);                                            \
        A2_ = fmaf(-2.f, p_, fmaf(98.f, sxy_, C2q));                         \
        B1_ = q_ + C1q;                                                      \
        B2_ = fmaf(49.f, tt_, C2q - q_);                                     \
        acc = fmaf(A1_ * A2_, __builtin_amdgcn_rcpf(B1_ * B2_), acc);        \
      }                                                                      \
      vxe += hxe - rxe[(J)]; vxo += hxo - rxo[(J)];                          \
      vye += hye - rye[(J)]; vyo += hyo - ryo[(J)];                          \
      vxxe += hxxe - rxxe[(J)]; vxxo += hxxo - rxxo[(J)];                    \
      vyye += hyye - ryye[(J)]; vyyo += hyyo - ryyo[(J)];                    \
      vxye += hxye - rxye[(J)]; vxyo += hxyo - rxyo[(J)];                    \
    } else {                                                                 \
      vxe += hxe; vxo += hxo; vye += hye; vyo += hyo;                        \
      vxxe += hxxe; vxxo += hxxo; vyye += hyye; vyyo += hyyo;                \
      vxye += hxye; vxyo += hxyo;                                            \
    }                                                                        \
    rxe[(J)] = hxe; rxo[(J)] = hxo; rye[(J)] = hye; ryo[(J)] = hyo;          \
    rxxe[(J)] = hxxe; rxxo[(J)] = hxxo; ryye[(J)] = hyye; ryyo[(J)] = hyyo;  \
    rxye[(J)] = hxye; rxyo[(J)] = hxyo;                                      \
  }

__global__ __launch_bounds__(64) void ssim_kernel(
    const float2* __restrict__ yp2, const float2* __restrict__ yt2,
    const float2* __restrict__ mk2, double* __restrict__ wsd,
    const unsigned* __restrict__ wsu) {
  const int bid = blockIdx.x;
  const int img = bid / (N_BANDS * N_STRIP);
  const int rem = bid % (N_BANDS * N_STRIP);
  const int band = rem / N_STRIP;
  const int strip = rem % N_STRIP;
  const int lane = threadIdx.x;
  const int nout = (strip < 3) ? 102 : 100;              // 3*102+2*100 = 506
  const int c0 = strip * 102 - ((strip == 4) ? 2 : 0);   // 0,102,204,306,406
  const int col2 = min(c0 + 2 * lane, IMG_W - 2);        // even, clamped
  const int r0 = band * BAND_H;
  const size_t base2 = (size_t)img * (IMG_HW / 2) + (size_t)r0 * (IMG_W / 2)
                       + (col2 >> 1);
  const bool prod = (lane < (nout >> 1));
  const bool mown = (strip < 4) ? (lane < (nout >> 1)) : (lane < 53);
  const bool lastband = (band == N_BANDS - 1);

  // bpermute byte addresses (hoisted)
  const int a1 = (lane + 1) << 2, a2 = (lane + 2) << 2, a3 = (lane + 3) << 2;

  const float d = funmap(wsu[48 + img]) - funmap(wsu[img]);
  const float C1q = (K1C * d) * (K1C * d) * 2401.0f;   // C1 * 49^2
  const float C2q = (K2C * d) * (K2C * d) * 2352.0f;   // C2 * 49*48

  // register rings: 5 quantities x 2 cols x 6 slots
  float rxe[6] = {0,0,0,0,0,0}, rxo[6] = {0,0,0,0,0,0};
  float rye[6] = {0,0,0,0,0,0}, ryo[6] = {0,0,0,0,0,0};
  float rxxe[6] = {0,0,0,0,0,0}, rxxo[6] = {0,0,0,0,0,0};
  float ryye[6] = {0,0,0,0,0,0}, ryyo[6] = {0,0,0,0,0,0};
  float rxye[6] = {0,0,0,0,0,0}, rxyo[6] = {0,0,0,0,0,0};
  float vxe = 0.f, vxo = 0.f, vye = 0.f, vyo = 0.f;
  float vxxe = 0.f, vxxo = 0.f, vyye = 0.f, vyyo = 0.f;
  float vxye = 0.f, vxyo = 0.f;
  float acc = 0.f, bs1 = 0.f, bs2 = 0.f;

  // Prologue: prefetch rows 0 (A) and 1 (B)
  float2 Ap = yp2[base2], At = yt2[base2], Am = mk2[base2];
  float2 Bp = yp2[base2 + IMG_W / 2], Bt = yt2[base2 + IMG_W / 2],
         Bm = mk2[base2 + IMG_W / 2];

  // warm-up rows 0..5 (ring slots 0..5; consume row R, reload row R+2)
  SEC(0, 0, A, true, true, 1)
  SEC(1, 1, B, true, true, 1)
  SEC(2, 2, A, true, true, 1)
  SEC(3, 3, B, true, true, 1)
  SEC(4, 4, A, true, true, 1)
  SEC(5, 5, B, true, true, 1)

  // rows 6..41: 6 groups of 6 (all owned)
  for (int g = 0; g < 6; ++g) {
    const int rbase = 6 + 6 * g;
    SEC(0, rbase + 0, A, false, true, 1)
    SEC(1, rbase + 1, B, false, true, 1)
    SEC(2, rbase + 2, A, false, true, 1)
    SEC(3, rbase + 3, B, false, true, 1)
    SEC(4, rbase + 4, A, false, true, 1)
    SEC(5, rbase + 5, B, false, true, 1)
  }
  // rows 42..47 (46,47 owned iff last band)
  SEC(0, 42, A, false, true, 1)
  SEC(1, 43, B, false, true, 1)
  SEC(2, 44, A, false, true, 1)
  SEC(3, 45, B, false, true, 1)
  SEC(4, 46, A, false, true, lastband)
  SEC(5, 47, B, false, true, lastband)
  // tail rows 48..51 (50,51 no reload; all conditional ownership)
  SEC(0, 48, A, false, true, lastband)
  SEC(1, 49, B, false, true, lastband)
  SEC(2, 50, A, false, false, lastband)
  SEC(3, 51, B, false, false, lastband)

  // wave reduction -> slotted accumulators (no barrier needed)
#pragma unroll
  for (int off = 32; off; off >>= 1) {
    acc += __shfl_down(acc, off);
    bs1 += __shfl_down(bs1, off);
    bs2 += __shfl_down(bs2, off);
  }
  if (lane == 0) {
    atomicAdd(&wsd[SLOT_SSIM + img * 8 + (rem & 7)], (double)acc);
    atomicAdd(&wsd[SLOT_S1 + (bid & 127)], (double)bs1);
    atomicAdd(&wsd[SLOT_S2 + (bid & 127)], (double)bs2);
  }
}

__global__ void finalize_kernel(const double* __restrict__ wsd,
                                float* __restrict__ out) {
  if (threadIdx.x == 0 && blockIdx.x == 0) {
    const double N = (double)N_IMG * (double)IMG_HW;   // 12582912
    double mae = 0.0, mse = 0.0, ssum = 0.0;
    for (int i = 0; i < 128; ++i) { mae += wsd[SLOT_S1 + i]; mse += wsd[SLOT_S2 + i]; }
    mae /= N; mse /= N;
    for (int i = 0; i < 384; ++i) ssum += wsd[SLOT_SSIM + i];
    double smean = ssum / ((double)OUT_W * (double)OUT_H * (double)N_IMG);
    double ssim_loss = 1.0 - smean;
    double total = 1.0 * mae + 0.5 * mse + 0.2 * ssim_loss;
    out[0] = (float)total;
    out[1] = (float)mae;
    out[2] = (float)mse;
    out[3] = (float)ssim_loss;
  }
}

extern "C" void kernel_launch(void* const* d_in, const int* in_sizes, int n_in,
                              void* d_out, int out_size, void* d_ws,
                              size_t ws_size, hipStream_t stream) {
  const float* yp = (const float*)d_in[0];
  const float* yt = (const float*)d_in[1];
  const float* mk = (const float*)d_in[2];
  float* out = (float*)d_out;
  double* wsd = (double*)d_ws;
  unsigned* wsu = (unsigned*)((char*)d_ws + WSU_OFF);

  hipLaunchKernelGGL(init_ws, dim3(1), dim3(1024), 0, stream, wsd, wsu);
  hipLaunchKernelGGL(range_kernel, dim3(N_IMG * 64), dim3(256), 0, stream,
                     (const float4*)yt, (const float4*)mk, wsu);
  hipLaunchKernelGGL(ssim_kernel, dim3(N_IMG * N_BANDS * N_STRIP), dim3(64),
                     0, stream, (const float2*)yp, (const float2*)yt,
                     (const float2*)mk, wsd, wsu);
  hipLaunchKernelGGL(finalize_kernel, dim3(1), dim3(64), 0, stream, wsd, out);
}